// Round 1
// baseline (193.909 us; speedup 1.0000x reference)
//
#include <hip/hip_runtime.h>
#include <hip/hip_bf16.h>

#define LB 2048
#define DB 256
#define HB 8
#define KB 64
#define BH 32   // B*H

typedef __attribute__((ext_vector_type(8))) short short8;
typedef __attribute__((ext_vector_type(4))) float floatx4;

// ---------------- projection: q = x@Wq + bq, k = x@Wk + bk, stored bf16 [BH][L][64]
// grid: 8192/16 = 512 blocks, 512 threads
__global__ __launch_bounds__(512) void proj_kernel(
    const float* __restrict__ x, const float* __restrict__ Wq,
    const float* __restrict__ bq, const float* __restrict__ Wk,
    const float* __restrict__ bk,
    __hip_bfloat16* __restrict__ qout, __hip_bfloat16* __restrict__ kout)
{
    __shared__ float xs[16][256];
    const int tid = threadIdx.x;
    const int l0 = blockIdx.x * 16;

    // stage 16x256 fp32 x-tile: 1024 float4, 2 per thread
    {
        const float4* src = reinterpret_cast<const float4*>(x + (size_t)l0 * DB);
        float4* dst = reinterpret_cast<float4*>(&xs[0][0]);
        dst[tid]       = src[tid];
        dst[tid + 512] = src[tid + 512];
    }
    __syncthreads();

    const int c = tid;          // output column 0..511
    const int h = c >> 6;
    const int kk = c & 63;

    float accq[16], acck[16];
#pragma unroll
    for (int r = 0; r < 16; ++r) { accq[r] = 0.f; acck[r] = 0.f; }

    const float4* xs4 = reinterpret_cast<const float4*>(&xs[0][0]); // [16][64]

#pragma unroll 2
    for (int d4 = 0; d4 < 64; ++d4) {
        const int dd = d4 * 4;
        const float wq0 = Wq[(dd + 0) * 512 + c];
        const float wq1 = Wq[(dd + 1) * 512 + c];
        const float wq2 = Wq[(dd + 2) * 512 + c];
        const float wq3 = Wq[(dd + 3) * 512 + c];
        const float wk0 = Wk[(dd + 0) * 512 + c];
        const float wk1 = Wk[(dd + 1) * 512 + c];
        const float wk2 = Wk[(dd + 2) * 512 + c];
        const float wk3 = Wk[(dd + 3) * 512 + c];
#pragma unroll
        for (int r = 0; r < 16; ++r) {
            const float4 xv = xs4[r * 64 + d4];
            accq[r] = fmaf(xv.w, wq3, fmaf(xv.z, wq2, fmaf(xv.y, wq1, fmaf(xv.x, wq0, accq[r]))));
            acck[r] = fmaf(xv.w, wk3, fmaf(xv.z, wk2, fmaf(xv.y, wk1, fmaf(xv.x, wk0, acck[r]))));
        }
    }

    const float biasq = bq[h];
    const float biask = bk[h];
#pragma unroll
    for (int r = 0; r < 16; ++r) {
        const int gr = l0 + r;
        const int b  = gr >> 11;
        const int l  = gr & (LB - 1);
        const size_t base = ((size_t)(b * HB + h) * LB + l) * KB + kk;
        qout[base] = __float2bfloat16(accq[r] + biasq);
        kout[base] = __float2bfloat16(acck[r] + biask);
    }
}

// ---------------- attention: online softmax + distance expectation
// grid: (32 q-tiles of 64 rows, 32 bh), block 256 (4 waves; wave w owns 16 rows)
__global__ __launch_bounds__(256) void attn_kernel(
    const __hip_bfloat16* __restrict__ qb, const __hip_bfloat16* __restrict__ kb,
    const float* __restrict__ prior_mean, const float* __restrict__ log_prior_std,
    float* __restrict__ out)
{
    const int tile = blockIdx.x;          // q-row tile of 64
    const int bh   = blockIdx.y;          // 0..31
    const int b    = bh >> 3;
    const int h    = bh & 7;
    const int wave = threadIdx.x >> 6;
    const int lane = threadIdx.x & 63;
    const int i0   = tile * 64 + wave * 16;
    const int lrow = lane & 15;
    const int kg   = lane >> 4;

    const float mu        = prior_mean[h];
    const float sigma     = expf(log_prior_std[h]);
    const float inv_sigma = 1.0f / sigma;
    // fold K^-0.5 and 1/(sigma*sqrt(2pi)) into one coefficient
    const float coef = 0.125f / (sigma * 2.5066282f);

    const size_t planebase = (size_t)bh * LB * KB;

    // A fragments: rows i0+lrow, k in [0,32) and [32,64), 8 contiguous bf16 per lane
    const short8* qrow = reinterpret_cast<const short8*>(
        qb + planebase + (size_t)(i0 + lrow) * KB + kg * 8);
    const short8 a0 = qrow[0];
    const short8 a1 = qrow[4];   // +32 bf16 elements

    float se[4] = {0.f, 0.f, 0.f, 0.f};
    float sw[4] = {0.f, 0.f, 0.f, 0.f};
    const float mcol = (float)lrow;
    const float irow_base = (float)(i0 + kg * 4);

    const __hip_bfloat16* kplane = kb + planebase;

    for (int mt = 0; mt < LB; mt += 16) {
        const short8* krow = reinterpret_cast<const short8*>(
            kplane + (size_t)(mt + lrow) * KB + kg * 8);
        const short8 b0 = krow[0];
        const short8 b1 = krow[4];
        floatx4 acc = {0.f, 0.f, 0.f, 0.f};
        acc = __builtin_amdgcn_mfma_f32_16x16x32_bf16(a0, b0, acc, 0, 0, 0);
        acc = __builtin_amdgcn_mfma_f32_16x16x32_bf16(a1, b1, acc, 0, 0, 0);

        const float mval = (float)mt + mcol;   // this lane's key column
#pragma unroll
        for (int r = 0; r < 4; ++r) {
            const float d  = mval - (irow_base + (float)r);
            const float t  = (d - mu) * inv_sigma;
            const float pr = coef * __expf(-0.5f * t * t);
            const float s  = acc[r] * pr;
            const float p  = __expf(s);          // scores ~1e-3, no max needed
            se[r] += p;
            sw[r]  = fmaf(p, d, sw[r]);
        }
    }

    // reduce over the 16 lanes sharing each output row (lane bits 0..3)
#pragma unroll
    for (int r = 0; r < 4; ++r) {
        float e = se[r], w = sw[r];
        for (int off = 8; off >= 1; off >>= 1) {
            e += __shfl_xor(e, off, 64);
            w += __shfl_xor(w, off, 64);
        }
        if (lrow == 0) {
            const int i = i0 + kg * 4 + r;
            out[((size_t)(b * LB + i)) * HB + h] = w / e;
        }
    }
}

extern "C" void kernel_launch(void* const* d_in, const int* in_sizes, int n_in,
                              void* d_out, int out_size, void* d_ws, size_t ws_size,
                              hipStream_t stream) {
    const float* x  = (const float*)d_in[0];
    const float* Wq = (const float*)d_in[1];
    const float* bq = (const float*)d_in[2];
    const float* Wk = (const float*)d_in[3];
    const float* bk = (const float*)d_in[4];
    const float* pm = (const float*)d_in[5];
    const float* ls = (const float*)d_in[6];
    float* out = (float*)d_out;

    __hip_bfloat16* qbuf = (__hip_bfloat16*)d_ws;
    __hip_bfloat16* kbuf = qbuf + (size_t)BH * LB * KB;   // +8.4 MB

    proj_kernel<<<dim3(512), dim3(512), 0, stream>>>(x, Wq, bq, Wk, bk, qbuf, kbuf);
    attn_kernel<<<dim3(32, 32), dim3(256), 0, stream>>>(qbuf, kbuf, pm, ls, out);
}